// Round 14
// baseline (249.223 us; speedup 1.0000x reference)
//
#include <hip/hip_runtime.h>
#include <hip/hip_bf16.h>
#include <stdint.h>

using bf16 = __hip_bfloat16;

typedef __bf16 bf16x8 __attribute__((ext_vector_type(8)));
typedef float  f32x4  __attribute__((ext_vector_type(4)));

__device__ __forceinline__ float bflo(uint32_t u) { return __uint_as_float(u << 16); }
__device__ __forceinline__ float bfhi(uint32_t u) { return __uint_as_float(u & 0xffff0000u); }

__device__ __forceinline__ void load8(const bf16* p, float* f) {
  uint4 u = *(const uint4*)p;
  f[0] = bflo(u.x); f[1] = bfhi(u.x);
  f[2] = bflo(u.y); f[3] = bfhi(u.y);
  f[4] = bflo(u.z); f[5] = bfhi(u.z);
  f[6] = bflo(u.w); f[7] = bfhi(u.w);
}
__device__ __forceinline__ void load8(const float* p, float* f) {
  float4 a = *(const float4*)p, b = *(const float4*)(p + 4);
  f[0] = a.x; f[1] = a.y; f[2] = a.z; f[3] = a.w;
  f[4] = b.x; f[5] = b.y; f[6] = b.z; f[7] = b.w;
}
__device__ __forceinline__ void store1(float* o, float v) { *o = v; }
__device__ __forceinline__ void store1(bf16* o, float v) { *o = __float2bfloat16(v); }
__device__ __forceinline__ uint32_t bfbits(float x) {
  bf16 v = __float2bfloat16(x);
  return (uint32_t)*(uint16_t*)&v;
}

// ---- async global->LDS, 16B per lane; lds base must be wave-uniform -------
typedef const uint32_t __attribute__((address_space(1)))* gp_t;
typedef uint32_t __attribute__((address_space(3)))* lp_t;
__device__ __forceinline__ void gload16(const void* g, void* l) {
  __builtin_amdgcn_global_load_lds((gp_t)g, (lp_t)l, 16, 0, 0);
}

// ---------------------------------------------------------------------------
// prep_mask: fused streaming kernel (one launch, 3077 blocks).
//  blocks 0..511    : mask_pack — x4-vectorized (R6-proven)
//  blocks 512..3071 : f32->bf16 of x,Wqkv,Wo,W1,W2 (1 unit/block)
//  blocks 3072..76  : Wp/Wc rows into wq rows 1536..1551 + bias concat
// ---------------------------------------------------------------------------
__global__ __launch_bounds__(256)
void prep_mask(const float* __restrict__ pm, const int* __restrict__ hid,
               const int* __restrict__ padm, uint32_t* __restrict__ mout,
               const float* __restrict__ x, const float* __restrict__ Wqkv,
               const float* __restrict__ Wo, const float* __restrict__ W1,
               const float* __restrict__ W2, bf16* __restrict__ xb,
               bf16* __restrict__ wq, bf16* __restrict__ wob,
               bf16* __restrict__ w1b, bf16* __restrict__ w2b,
               const float* __restrict__ bqkv, const float* __restrict__ bp,
               const float* __restrict__ bc, const float* __restrict__ Wp,
               const float* __restrict__ Wc, float* __restrict__ bias_ext)
{
  __shared__ ushort tileT[128][70];   // bf16 bits of pm^T; stride 70
  const int t = threadIdx.x;
  if (blockIdx.x < 512) {
    // ---- mask_pack (x4 vectorized)
    const int mb = blockIdx.x;
    const int k0 = (mb & 7) * 128, q0 = ((mb >> 3) & 15) * 64, b = mb >> 7;
    const size_t pb = (size_t)b << 20;
#pragma unroll
    for (int i = 0; i < 8; ++i) {
      int idx = t + i * 256;               // [0, 2048)
      int r = idx >> 4, c4 = (idx & 15) * 4;
      float4 v = *(const float4*)(pm + pb + (size_t)(k0 + r) * 1024 + q0 + c4);
      tileT[r][c4 + 0] = (ushort)bfbits(v.x);
      tileT[r][c4 + 1] = (ushort)bfbits(v.y);
      tileT[r][c4 + 2] = (ushort)bfbits(v.z);
      tileT[r][c4 + 3] = (ushort)bfbits(v.w);
    }
    __syncthreads();
#pragma unroll
    for (int i = 0; i < 8; ++i) {
      int idx = t + i * 256;               // [0, 2048)
      int q = idx >> 5, k4 = (idx & 31) * 4;
      size_t src = pb + (size_t)(q0 + q) * 1024 + k0 + k4;
      int4  hv = *(const int4*)(hid + src);
      float4 pv = *(const float4*)(pm + src);
      int4  pd = *(const int4*)(padm + b * 1024 + k0 + k4);
      uint4 o;
      o.x = (hv.x | pd.x) ? 0xFFFFFFFFu : (((uint32_t)tileT[k4 + 0][q] << 16) | bfbits(pv.x));
      o.y = (hv.y | pd.y) ? 0xFFFFFFFFu : (((uint32_t)tileT[k4 + 1][q] << 16) | bfbits(pv.y));
      o.z = (hv.z | pd.z) ? 0xFFFFFFFFu : (((uint32_t)tileT[k4 + 2][q] << 16) | bfbits(pv.z));
      o.w = (hv.w | pd.w) ? 0xFFFFFFFFu : (((uint32_t)tileT[k4 + 3][q] << 16) | bfbits(pv.w));
      *(uint4*)(mout + src) = o;
    }
    return;
  }
  const int blk = blockIdx.x - 512;
  if (blk < 2560) {
    size_t j = ((size_t)blk * 256 + t) * 8;
    const float* s; bf16* o; size_t off;
    if      (j < 2097152) { s = x;    o = xb;  off = j; }
    else if (j < 2883584) { s = Wqkv; o = wq;  off = j - 2097152; }
    else if (j < 3145728) { s = Wo;   o = wob; off = j - 2883584; }
    else if (j < 4194304) { s = W1;   o = w1b; off = j - 3145728; }
    else                  { s = W2;   o = w2b; off = j - 4194304; }
    float f[8];
    load8(s + off, f);
    uint4 u;
    u.x = (bfbits(f[1]) << 16) | bfbits(f[0]);
    u.y = (bfbits(f[3]) << 16) | bfbits(f[2]);
    u.z = (bfbits(f[5]) << 16) | bfbits(f[4]);
    u.w = (bfbits(f[7]) << 16) | bfbits(f[6]);
    *(uint4*)(o + off) = u;
  } else {
    int sb = blk - 2560;
    if (sb < 2) {
      int j = (sb * 256 + t) * 8;
      if (j < 4096) {
        float f[8]; load8(Wp + j, f);
#pragma unroll
        for (int i = 0; i < 8; ++i) wq[(size_t)1536 * 512 + j + i] = __float2bfloat16(f[i]);
      }
    } else if (sb < 4) {
      int j = ((sb - 2) * 256 + t) * 8;
      if (j < 4096) {
        float f[8]; load8(Wc + j, f);
#pragma unroll
        for (int i = 0; i < 8; ++i) wq[(size_t)1544 * 512 + j + i] = __float2bfloat16(f[i]);
      }
    } else {
      int j = t * 8;
#pragma unroll
      for (int i = 0; i < 8; ++i) {
        int cc = j + i;
        if (cc < 1664) {
          float v = 0.f;
          if (cc < 1536) v = bqkv[cc];
          else if (cc < 1544) v = bp[cc - 1536];
          else if (cc < 1552) v = bc[cc - 1544];
          bias_ext[cc] = v;
        }
      }
    }
  }
}

// ---------------------------------------------------------------------------
// qkv_gemm: 128x128 MFMA gemm C = xb * wq^T + bias, with the QKV + pb/cb
// scatter epilogue. M=4096, Nout=1664, K=512. Double-buffered LDS 2-phase.
// ---------------------------------------------------------------------------
__global__ __launch_bounds__(256)
void qkv_gemm(const bf16* __restrict__ A, const bf16* __restrict__ W,
              const float* __restrict__ bias, bf16* __restrict__ outb,
              float* __restrict__ outf)
{
  __shared__ bf16 As[2][128 * 64];
  __shared__ bf16 Bs[2][128 * 64];
  const int t = threadIdx.x;
  const int lane = t & 63, wave = t >> 6;
  const int m0 = (blockIdx.x / 13) * 128, n0 = (blockIdx.x % 13) * 128;
  const int wr = wave >> 1, wc = wave & 1;
  const int frow = lane & 15, ksel = (lane >> 4) * 8;
  f32x4 acc[16] = {};
  const bf16* Ab = A + (size_t)m0 * 512;
  const bf16* Wb = W + (size_t)n0 * 512;

  const int ibs = wave * 64 + lane;            // per-lane stage index base
#define STAGE(buf, k0)                                                        \
  {                                                                           \
    _Pragma("unroll")                                                         \
    for (int i = 0; i < 4; ++i) {                                             \
      int idx = i * 256 + ibs;                                                \
      gload16(Ab + (size_t)(idx >> 3) * 512 + (k0) + (idx & 7) * 8,           \
              &As[buf][(i * 256 + wave * 64) * 8]);                           \
    }                                                                         \
    _Pragma("unroll")                                                         \
    for (int i = 0; i < 4; ++i) {                                             \
      int idx = i * 256 + ibs;                                                \
      gload16(Wb + (size_t)(idx >> 3) * 512 + (k0) + (idx & 7) * 8,           \
              &Bs[buf][(i * 256 + wave * 64) * 8]);                           \
    }                                                                         \
  }

  STAGE(0, 0);
  __syncthreads();                       // buf0 ready
#pragma unroll
  for (int ks = 0; ks < 8; ++ks) {
    const int cur = ks & 1;
    if (ks < 7) STAGE(cur ^ 1, (ks + 1) * 64);   // in flight during compute
#pragma unroll
    for (int kk = 0; kk < 64; kk += 32) {
      bf16x8 af[4], bf_[4];
#pragma unroll
      for (int mt = 0; mt < 4; ++mt)
        af[mt] = *(const bf16x8*)(&As[cur][(wr * 64 + mt * 16 + frow) * 64 + kk + ksel]);
#pragma unroll
      for (int nt = 0; nt < 4; ++nt)
        bf_[nt] = *(const bf16x8*)(&Bs[cur][(wc * 64 + nt * 16 + frow) * 64 + kk + ksel]);
#pragma unroll
      for (int mt = 0; mt < 4; ++mt)
#pragma unroll
        for (int nt = 0; nt < 4; ++nt)
          acc[mt * 4 + nt] = __builtin_amdgcn_mfma_f32_16x16x32_bf16(
              af[mt], bf_[nt], acc[mt * 4 + nt], 0, 0, 0);
    }
    __syncthreads();                     // drains next-stage DMA + guards reuse
  }
#undef STAGE

  const int rb = (lane >> 4) * 4, cb = lane & 15;
#pragma unroll
  for (int mt = 0; mt < 4; ++mt)
#pragma unroll
    for (int nt = 0; nt < 4; ++nt) {
      f32x4 a = acc[mt * 4 + nt];
#pragma unroll
      for (int r = 0; r < 4; ++r) {
        int row = m0 + wr * 64 + mt * 16 + rb + r;
        int col = n0 + wc * 64 + nt * 16 + cb;
        if (col >= 1552) continue;             // padding cols
        float v = a[r] + bias[col];
        int n = row >> 2, b = row & 3;
        if (col >= 1536) {                     // pb/cb projections, f32
          int j = col - 1536;
          int hh = j & 7;
          outf[(j < 8 ? 0 : 32768) + (b * 8 + hh) * 1024 + n] = v;
        } else {
          int which = col >> 9, hh = (col >> 6) & 7, d = col & 63;
          if (which == 0) v *= 0.125f;         // fold 1/sqrt(HD) into Q
          size_t idx;
          if (which == 2)   // V transposed: [b][h][d][n]
            idx = (((size_t)(64 + b * 8 + hh)) << 16) + (size_t)d * 1024 + n;
          else              // Q,K: [which][b][h][n][d]
            idx = (((size_t)(which * 32 + b * 8 + hh)) << 16) + (size_t)n * 64 + d;
          outb[idx] = __float2bfloat16(v);
        }
      }
    }
}

// ---------------------------------------------------------------------------
// GEMM: C[M,Nout] = A[M,K(kOff..kOff+kLen)] * W^T + bias   (bf16, f32 accum)
// 128 x BN tile, global_load_lds(16B) staging, 4 waves, single-buffered.
// MODE 0: bf16 store. MODE 1: relu+bf16. MODE 4: bf16 split-K partial.
// ---------------------------------------------------------------------------
template<int MODE, int BN>
__global__ __launch_bounds__(256)
void gemm_bt(const bf16* __restrict__ A, const bf16* __restrict__ W,
             const float* __restrict__ bias, bf16* __restrict__ outb,
             float* __restrict__ outf, int M, int Nout, int K, int kLen)
{
  constexpr int NT = BN / 32;
  __shared__ bf16 As[128 * 64];
  __shared__ bf16 Bs[BN * 64];
  const int t = threadIdx.x, lane = t & 63, wave = t >> 6;
  const int m0 = blockIdx.y * 128, n0 = blockIdx.x * BN;
  const int kOff = blockIdx.z * kLen;
  if (MODE == 4) outb += (size_t)blockIdx.z * M * Nout;
  const int wr = wave >> 1, wc = wave & 1;
  const int frow = lane & 15, ksel = (lane >> 4) * 8;
  f32x4 acc[4 * NT] = {};
  const bf16* Ab = A + (size_t)m0 * K;
  const bf16* Wb = W + (size_t)n0 * K;

  for (int k0 = kOff; k0 < kOff + kLen; k0 += 64) {
    __syncthreads();
#pragma unroll
    for (int i = 0; i < 4; ++i) {
      int ib = i * 256 + wave * 64;
      int idx = ib + lane;
      gload16(Ab + (size_t)(idx >> 3) * K + k0 + (idx & 7) * 8, As + ib * 8);
    }
#pragma unroll
    for (int i = 0; i < BN / 32; ++i) {
      int ib = i * 256 + wave * 64;
      int idx = ib + lane;
      gload16(Wb + (size_t)(idx >> 3) * K + k0 + (idx & 7) * 8, Bs + ib * 8);
    }
    __syncthreads();
#pragma unroll
    for (int kk = 0; kk < 64; kk += 32) {
      bf16x8 af[4], bf_[NT];
#pragma unroll
      for (int mt = 0; mt < 4; ++mt)
        af[mt] = *(const bf16x8*)(As + (wr * 64 + mt * 16 + frow) * 64 + kk + ksel);
#pragma unroll
      for (int nt = 0; nt < NT; ++nt)
        bf_[nt] = *(const bf16x8*)(Bs + (wc * (BN / 2) + nt * 16 + frow) * 64 + kk + ksel);
#pragma unroll
      for (int mt = 0; mt < 4; ++mt)
#pragma unroll
        for (int nt = 0; nt < NT; ++nt)
          acc[mt * NT + nt] = __builtin_amdgcn_mfma_f32_16x16x32_bf16(
              af[mt], bf_[nt], acc[mt * NT + nt], 0, 0, 0);
    }
  }
  const int rb = (lane >> 4) * 4, cb = lane & 15;
#pragma unroll
  for (int mt = 0; mt < 4; ++mt)
#pragma unroll
    for (int nt = 0; nt < NT; ++nt) {
      f32x4 a = acc[mt * NT + nt];
#pragma unroll
      for (int r = 0; r < 4; ++r) {
        int row = m0 + wr * 64 + mt * 16 + rb + r;
        int col = n0 + wc * (BN / 2) + nt * 16 + cb;
        if (MODE == 4) {
          outb[(size_t)row * Nout + col] = __float2bfloat16(a[r]);
        } else {
          float v = a[r] + bias[col];
          if (MODE == 1) v = fmaxf(v, 0.f);
          outb[(size_t)row * Nout + col] = __float2bfloat16(v);
        }
      }
    }
}

// ---------------------------------------------------------------------------
// MFMA flash attention, S^T form, UN-split KV (full 1024 keys per block).
// R3/R6-proven body. GRID ORDER SWAPPED: x=h (innermost), y=qchunk, z=b —
// the 8 h-blocks sharing identical mask rows + pb/cb are now dispatch-
// adjacent -> XCD-L2 hits on the 256KB of mask they share (was stride-16
// apart -> evicted between uses; FETCH 43.2MB vs 29.4MB logical).
// ---------------------------------------------------------------------------
__global__ __launch_bounds__(256, 2)
void attn_mfma(const bf16* __restrict__ qkv, const float* __restrict__ pbw,
               const float* __restrict__ cbw, const uint32_t* __restrict__ mpk,
               bf16* __restrict__ ctxo)
{
  __shared__ bf16 Kt[128 * 64];    // [key][d] swizzled (DMA)
  __shared__ bf16 Vt[64 * 128];    // [d][key] swizzled (DMA)
  __shared__ bf16 Ps[4][16][136];  // per-wave P [q][key], stride 136 -> 2-way
  const int t = threadIdx.x, lane = t & 63, wave = t >> 6;
  const int g = lane >> 4, c = lane & 15;
  const int h = blockIdx.x, b = blockIdx.z;
  const int q0 = blockIdx.y * 64 + wave * 16;
  const size_t bh = (size_t)b * 8 + h;
  const bf16* Qp = qkv + (bh << 16);
  const bf16* Kp = qkv + ((32 + bh) << 16);
  const bf16* Vg = qkv + ((64 + bh) << 16);     // [64 d][1024 n]

  bf16x8 qa0 = *(const bf16x8*)(Qp + (size_t)(q0 + c) * 64 + g * 8);
  bf16x8 qa1 = *(const bf16x8*)(Qp + (size_t)(q0 + c) * 64 + 32 + g * 8);

  const float pbq = pbw[bh * 1024 + q0 + c];
  const float cbq = cbw[bh * 1024 + q0 + c];
  const uint32_t* mrp = mpk + (((size_t)b * 1024 + q0 + c) << 10);

  f32x4 oacc[4] = {{0,0,0,0},{0,0,0,0},{0,0,0,0},{0,0,0,0}};
  float m = -1e30f, l = 0.f;

  for (int kt = 0; kt < 8; ++kt) {
    const int k0 = kt * 128;
    __syncthreads();
#pragma unroll
    for (int i = 0; i < 4; ++i) {    // K DMA: slot (r,p) <- chunk p^(r&7)
      int ib = i * 256 + wave * 64;
      int idx = ib + lane;
      int r = idx >> 3, p = idx & 7;
      gload16(Kp + (size_t)(k0 + r) * 64 + ((p ^ (r & 7)) * 8), Kt + ib * 8);
    }
#pragma unroll
    for (int i = 0; i < 4; ++i) {    // V DMA: slot (d,p) <- chunk p^(d&15)
      int ib = i * 256 + wave * 64;
      int idx = ib + lane;
      int d = idx >> 4, p = idx & 15;
      gload16(Vg + (size_t)d * 1024 + k0 + ((p ^ (d & 15)) * 8), Vt + ib * 8);
    }
    uint4 mu[8];
#pragma unroll
    for (int nt = 0; nt < 8; ++nt)
      mu[nt] = *(const uint4*)(mrp + k0 + nt * 16 + 4 * g);
    __syncthreads();
    f32x4 sacc[8];
#pragma unroll
    for (int nt = 0; nt < 8; ++nt) {
      f32x4 z = {0.f,0.f,0.f,0.f};
      int r = nt * 16 + c;           // r & 7 == c & 7
      bf16x8 k0f = *(const bf16x8*)(Kt + r * 64 + (( g      ^ (c & 7)) * 8));
      bf16x8 k1f = *(const bf16x8*)(Kt + r * 64 + (((4 + g) ^ (c & 7)) * 8));
      z = __builtin_amdgcn_mfma_f32_16x16x32_bf16(k0f, qa0, z, 0, 0, 0);
      z = __builtin_amdgcn_mfma_f32_16x16x32_bf16(k1f, qa1, z, 0, 0, 0);
      sacc[nt] = z;
    }
    float mx = -1e30f;
#pragma unroll
    for (int nt = 0; nt < 8; ++nt) {
      uint32_t uu[4] = {mu[nt].x, mu[nt].y, mu[nt].z, mu[nt].w};
#pragma unroll
      for (int r = 0; r < 4; ++r) {
        float s = sacc[nt][r] + bfhi(uu[r]) * pbq + bflo(uu[r]) * cbq;
        s = (uu[r] == 0xFFFFFFFFu) ? -1e30f : s;
        sacc[nt][r] = s;
        mx = fmaxf(mx, s);
      }
    }
    mx = fmaxf(mx, __shfl_xor(mx, 16));
    mx = fmaxf(mx, __shfl_xor(mx, 32));
    const float newm = fmaxf(m, mx);
    const float al = __expf(m - newm);
    float ps = 0.f;
#pragma unroll
    for (int nt = 0; nt < 8; ++nt) {
      float p0 = (sacc[nt][0] <= -1e29f) ? 0.f : __expf(sacc[nt][0] - newm);
      float p1 = (sacc[nt][1] <= -1e29f) ? 0.f : __expf(sacc[nt][1] - newm);
      float p2 = (sacc[nt][2] <= -1e29f) ? 0.f : __expf(sacc[nt][2] - newm);
      float p3 = (sacc[nt][3] <= -1e29f) ? 0.f : __expf(sacc[nt][3] - newm);
      ps += (p0 + p1) + (p2 + p3);
      uint2 w;
      w.x = (bfbits(p1) << 16) | bfbits(p0);
      w.y = (bfbits(p3) << 16) | bfbits(p2);
      *(uint2*)&Ps[wave][c][nt * 16 + 4 * g] = w;
    }
    ps += __shfl_xor(ps, 16);
    ps += __shfl_xor(ps, 32);
    l = l * al + ps;
    m = newm;
#pragma unroll
    for (int dt = 0; dt < 4; ++dt) {
      oacc[dt][0] *= al; oacc[dt][1] *= al;
      oacc[dt][2] *= al; oacc[dt][3] *= al;
    }
#pragma unroll
    for (int dt = 0; dt < 4; ++dt) {
      int row = dt * 16 + c;         // row & 15 == c
#pragma unroll
      for (int kc = 0; kc < 4; ++kc) {
        bf16x8 vf = *(const bf16x8*)(Vt + row * 128 + (((kc * 4 + g) ^ c) * 8));
        bf16x8 pf = *(const bf16x8*)&Ps[wave][c][kc * 32 + g * 8];
        oacc[dt] = __builtin_amdgcn_mfma_f32_16x16x32_bf16(vf, pf, oacc[dt], 0, 0, 0);
      }
    }
  }
  // normalized direct write: ctx[(q*4 + b)*512 + h*64 + d], bf16
  const int qg = q0 + c;
  const float inv = (l > 0.f) ? 1.f / l : 0.f;
  bf16* out = ctxo + ((size_t)qg * 4 + b) * 512 + h * 64;
#pragma unroll
  for (int dt = 0; dt < 4; ++dt) {
    uint2 w;
    w.x = (bfbits(oacc[dt][1] * inv) << 16) | bfbits(oacc[dt][0] * inv);
    w.y = (bfbits(oacc[dt][3] * inv) << 16) | bfbits(oacc[dt][2] * inv);
    *(uint2*)(out + dt * 16 + 4 * g) = w;
  }
}

// ---------------------------------------------------------------------------
// out = LayerNorm(a + p0 + p1 + bias) * g + be   (row = 512, wave per row)
// TP = partial dtype (bf16 — halves split-K read traffic, R13-proven).
// ---------------------------------------------------------------------------
template<typename TA, typename TP, typename TO>
__global__ __launch_bounds__(256)
void ln_res2(const TA* __restrict__ a, const TP* __restrict__ p0,
             const TP* __restrict__ p1, const float* __restrict__ bias,
             const float* __restrict__ g, const float* __restrict__ be,
             TO* __restrict__ out)
{
  const int wave = threadIdx.x >> 6, lane = threadIdx.x & 63;
  const int m = blockIdx.x * 4 + wave;
  const size_t base = (size_t)m * 512 + lane * 8;
  float va[8], f0[8], f1[8], bb[8];
  load8(a + base, va);
  load8(p0 + base, f0);
  load8(p1 + base, f1);
  load8(bias + lane * 8, bb);
  float v[8], s = 0.f;
#pragma unroll
  for (int j = 0; j < 8; ++j) { v[j] = va[j] + f0[j] + f1[j] + bb[j]; s += v[j]; }
#pragma unroll
  for (int off = 32; off; off >>= 1) s += __shfl_xor(s, off);
  const float mean = s * (1.f / 512.f);
  float q = 0.f;
#pragma unroll
  for (int j = 0; j < 8; ++j) { float d = v[j] - mean; q += d * d; }
#pragma unroll
  for (int off = 32; off; off >>= 1) q += __shfl_xor(q, off);
  const float rs = rsqrtf(q * (1.f / 512.f) + 1e-5f);
  float gv[8], bv[8];
  load8(g + lane * 8, gv);
  load8(be + lane * 8, bv);
#pragma unroll
  for (int j = 0; j < 8; ++j)
    store1(out + base + j, (v[j] - mean) * rs * gv[j] + bv[j]);
}

// ---------------------------------------------------------------------------
extern "C" void kernel_launch(void* const* d_in, const int* in_sizes, int n_in,
                              void* d_out, int out_size, void* d_ws, size_t ws_size,
                              hipStream_t stream)
{
  (void)in_sizes; (void)n_in; (void)out_size; (void)ws_size;
  const float* x    = (const float*)d_in[0];
  const float* pm   = (const float*)d_in[1];
  const int*   hid  = (const int*)d_in[2];
  const int*   padm = (const int*)d_in[3];
  const float* Wp   = (const float*)d_in[4];
  const float* bp   = (const float*)d_in[5];
  const float* Wc   = (const float*)d_in[6];
  const float* bc   = (const float*)d_in[7];
  const float* Wqkv = (const float*)d_in[8];
  const float* bqkv = (const float*)d_in[9];
  const float* Wo   = (const float*)d_in[10];
  const float* bo   = (const float*)d_in[11];
  const float* W1   = (const float*)d_in[12];
  const float* b1   = (const float*)d_in[13];
  const float* W2   = (const float*)d_in[14];
  const float* b2   = (const float*)d_in[15];
  const float* g1   = (const float*)d_in[16];
  const float* be1  = (const float*)d_in[17];
  const float* g2   = (const float*)d_in[18];
  const float* be2  = (const float*)d_in[19];

  // Workspace (lifetimes):
  char* ws = (char*)d_ws;
  bf16*     qkvb  = (bf16*)    (ws);               // 12.58 MB (qkv_gemm -> attn)
  float*    pbo   = (float*)   (ws + 12582912);    // 128 KB
  float*    cbo   = (float*)   (ws + 12713984);    // 128 KB  (= pbo + 32768 el)
  uint32_t* mpk   = (uint32_t*)(ws + 12845056);    // 16.78 MB (prep_mask -> attn)
  bf16*     ctx   = (bf16*)    (ws + 29622272);    // 4.19 MB (attn -> Wo gemm)
  bf16*     partb = (bf16*)    (ws);               // 8.39 MB bf16 split-K partials
  bf16*     ff1   = (bf16*)    (ws + 16777216);    // 16.78 MB (aliases mpk tail + ctx)
  bf16*     y     = (bf16*)    (ws + 33816576);    // 4.19 MB (ln1 -> ln2)
  bf16*     xb    = (bf16*)    (ws + 38010880);    // 4.19 MB
  bf16*     wqkvb = (bf16*)    (ws + 42205184);    // 1.70 MB (1664 x 512 bf16)
  bf16*     wob   = (bf16*)    (ws + 43909120);    // 512 KB
  bf16*     w1b   = (bf16*)    (ws + 44433408);    // 2.10 MB
  bf16*     w2b   = (bf16*)    (ws + 46530560);    // 2.10 MB
  float*    bext  = (float*)   (ws + 48627712);    // 6.5 KB
  bf16*     partb1 = partb + (size_t)4096 * 512;

  prep_mask<<<3077, 256, 0, stream>>>(pm, hid, padm, mpk,
                                      x, Wqkv, Wo, W1, W2, xb, wqkvb, wob, w1b, w2b,
                                      bqkv, bp, bc, Wp, Wc, bext);
  qkv_gemm<<<416, 256, 0, stream>>>(xb, wqkvb, bext, qkvb, pbo);
  attn_mfma<<<dim3(8, 16, 4), 256, 0, stream>>>(qkvb, pbo, cbo, mpk, ctx);
  gemm_bt<4, 64><<<dim3(8, 32, 2), 256, 0, stream>>>(ctx, wob, nullptr, partb, nullptr, 4096, 512, 512, 256);
  ln_res2<bf16, bf16, bf16><<<1024, 256, 0, stream>>>(xb, partb, partb1, bo, g1, be1, y);
  gemm_bt<1, 128><<<dim3(16, 32), 256, 0, stream>>>(y, w1b, b1, ff1, nullptr, 4096, 2048, 512, 512);
  gemm_bt<4, 64><<<dim3(8, 32, 2), 256, 0, stream>>>(ff1, w2b, nullptr, partb, nullptr, 4096, 512, 2048, 1024);
  ln_res2<bf16, bf16, float><<<1024, 256, 0, stream>>>(y, partb, partb1, b2, g2, be2, (float*)d_out);
}

// Round 15
// 245.630 us; speedup vs baseline: 1.0146x; 1.0146x over previous
//
#include <hip/hip_runtime.h>
#include <hip/hip_bf16.h>
#include <stdint.h>

using bf16 = __hip_bfloat16;

typedef __bf16 bf16x8 __attribute__((ext_vector_type(8)));
typedef float  f32x4  __attribute__((ext_vector_type(4)));

__device__ __forceinline__ float bflo(uint32_t u) { return __uint_as_float(u << 16); }
__device__ __forceinline__ float bfhi(uint32_t u) { return __uint_as_float(u & 0xffff0000u); }

__device__ __forceinline__ void load8(const bf16* p, float* f) {
  uint4 u = *(const uint4*)p;
  f[0] = bflo(u.x); f[1] = bfhi(u.x);
  f[2] = bflo(u.y); f[3] = bfhi(u.y);
  f[4] = bflo(u.z); f[5] = bfhi(u.z);
  f[6] = bflo(u.w); f[7] = bfhi(u.w);
}
__device__ __forceinline__ void load8(const float* p, float* f) {
  float4 a = *(const float4*)p, b = *(const float4*)(p + 4);
  f[0] = a.x; f[1] = a.y; f[2] = a.z; f[3] = a.w;
  f[4] = b.x; f[5] = b.y; f[6] = b.z; f[7] = b.w;
}
__device__ __forceinline__ void store1(float* o, float v) { *o = v; }
__device__ __forceinline__ void store1(bf16* o, float v) { *o = __float2bfloat16(v); }
__device__ __forceinline__ uint32_t bfbits(float x) {
  bf16 v = __float2bfloat16(x);
  return (uint32_t)*(uint16_t*)&v;
}

// ---- async global->LDS, 16B per lane; lds base must be wave-uniform -------
typedef const uint32_t __attribute__((address_space(1)))* gp_t;
typedef uint32_t __attribute__((address_space(3)))* lp_t;
__device__ __forceinline__ void gload16(const void* g, void* l) {
  __builtin_amdgcn_global_load_lds((gp_t)g, (lp_t)l, 16, 0, 0);
}

// ---------------------------------------------------------------------------
// prep_mask: fused streaming kernel (one launch, 3077 blocks).
//  blocks 0..511    : mask_pack — x4-vectorized (R6-proven)
//  blocks 512..3071 : f32->bf16 of x,Wqkv,Wo,W1,W2 (1 unit/block)
//  blocks 3072..76  : Wp/Wc rows into wq rows 1536..1551 + bias concat
// ---------------------------------------------------------------------------
__global__ __launch_bounds__(256)
void prep_mask(const float* __restrict__ pm, const int* __restrict__ hid,
               const int* __restrict__ padm, uint32_t* __restrict__ mout,
               const float* __restrict__ x, const float* __restrict__ Wqkv,
               const float* __restrict__ Wo, const float* __restrict__ W1,
               const float* __restrict__ W2, bf16* __restrict__ xb,
               bf16* __restrict__ wq, bf16* __restrict__ wob,
               bf16* __restrict__ w1b, bf16* __restrict__ w2b,
               const float* __restrict__ bqkv, const float* __restrict__ bp,
               const float* __restrict__ bc, const float* __restrict__ Wp,
               const float* __restrict__ Wc, float* __restrict__ bias_ext)
{
  __shared__ ushort tileT[128][70];   // bf16 bits of pm^T; stride 70
  const int t = threadIdx.x;
  if (blockIdx.x < 512) {
    // ---- mask_pack (x4 vectorized)
    const int mb = blockIdx.x;
    const int k0 = (mb & 7) * 128, q0 = ((mb >> 3) & 15) * 64, b = mb >> 7;
    const size_t pb = (size_t)b << 20;
#pragma unroll
    for (int i = 0; i < 8; ++i) {
      int idx = t + i * 256;               // [0, 2048)
      int r = idx >> 4, c4 = (idx & 15) * 4;
      float4 v = *(const float4*)(pm + pb + (size_t)(k0 + r) * 1024 + q0 + c4);
      tileT[r][c4 + 0] = (ushort)bfbits(v.x);
      tileT[r][c4 + 1] = (ushort)bfbits(v.y);
      tileT[r][c4 + 2] = (ushort)bfbits(v.z);
      tileT[r][c4 + 3] = (ushort)bfbits(v.w);
    }
    __syncthreads();
#pragma unroll
    for (int i = 0; i < 8; ++i) {
      int idx = t + i * 256;               // [0, 2048)
      int q = idx >> 5, k4 = (idx & 31) * 4;
      size_t src = pb + (size_t)(q0 + q) * 1024 + k0 + k4;
      int4  hv = *(const int4*)(hid + src);
      float4 pv = *(const float4*)(pm + src);
      int4  pd = *(const int4*)(padm + b * 1024 + k0 + k4);
      uint4 o;
      o.x = (hv.x | pd.x) ? 0xFFFFFFFFu : (((uint32_t)tileT[k4 + 0][q] << 16) | bfbits(pv.x));
      o.y = (hv.y | pd.y) ? 0xFFFFFFFFu : (((uint32_t)tileT[k4 + 1][q] << 16) | bfbits(pv.y));
      o.z = (hv.z | pd.z) ? 0xFFFFFFFFu : (((uint32_t)tileT[k4 + 2][q] << 16) | bfbits(pv.z));
      o.w = (hv.w | pd.w) ? 0xFFFFFFFFu : (((uint32_t)tileT[k4 + 3][q] << 16) | bfbits(pv.w));
      *(uint4*)(mout + src) = o;
    }
    return;
  }
  const int blk = blockIdx.x - 512;
  if (blk < 2560) {
    size_t j = ((size_t)blk * 256 + t) * 8;
    const float* s; bf16* o; size_t off;
    if      (j < 2097152) { s = x;    o = xb;  off = j; }
    else if (j < 2883584) { s = Wqkv; o = wq;  off = j - 2097152; }
    else if (j < 3145728) { s = Wo;   o = wob; off = j - 2883584; }
    else if (j < 4194304) { s = W1;   o = w1b; off = j - 3145728; }
    else                  { s = W2;   o = w2b; off = j - 4194304; }
    float f[8];
    load8(s + off, f);
    uint4 u;
    u.x = (bfbits(f[1]) << 16) | bfbits(f[0]);
    u.y = (bfbits(f[3]) << 16) | bfbits(f[2]);
    u.z = (bfbits(f[5]) << 16) | bfbits(f[4]);
    u.w = (bfbits(f[7]) << 16) | bfbits(f[6]);
    *(uint4*)(o + off) = u;
  } else {
    int sb = blk - 2560;
    if (sb < 2) {
      int j = (sb * 256 + t) * 8;
      if (j < 4096) {
        float f[8]; load8(Wp + j, f);
#pragma unroll
        for (int i = 0; i < 8; ++i) wq[(size_t)1536 * 512 + j + i] = __float2bfloat16(f[i]);
      }
    } else if (sb < 4) {
      int j = ((sb - 2) * 256 + t) * 8;
      if (j < 4096) {
        float f[8]; load8(Wc + j, f);
#pragma unroll
        for (int i = 0; i < 8; ++i) wq[(size_t)1544 * 512 + j + i] = __float2bfloat16(f[i]);
      }
    } else {
      int j = t * 8;
#pragma unroll
      for (int i = 0; i < 8; ++i) {
        int cc = j + i;
        if (cc < 1664) {
          float v = 0.f;
          if (cc < 1536) v = bqkv[cc];
          else if (cc < 1544) v = bp[cc - 1536];
          else if (cc < 1552) v = bc[cc - 1544];
          bias_ext[cc] = v;
        }
      }
    }
  }
}

// ---------------------------------------------------------------------------
// qkv_gemm: 128x128 MFMA gemm C = xb * wq^T + bias, with the QKV + pb/cb
// scatter epilogue. M=4096, Nout=1664, K=512. Double-buffered LDS 2-phase.
// ---------------------------------------------------------------------------
__global__ __launch_bounds__(256)
void qkv_gemm(const bf16* __restrict__ A, const bf16* __restrict__ W,
              const float* __restrict__ bias, bf16* __restrict__ outb,
              float* __restrict__ outf)
{
  __shared__ bf16 As[2][128 * 64];
  __shared__ bf16 Bs[2][128 * 64];
  const int t = threadIdx.x;
  const int lane = t & 63, wave = t >> 6;
  const int m0 = (blockIdx.x / 13) * 128, n0 = (blockIdx.x % 13) * 128;
  const int wr = wave >> 1, wc = wave & 1;
  const int frow = lane & 15, ksel = (lane >> 4) * 8;
  f32x4 acc[16] = {};
  const bf16* Ab = A + (size_t)m0 * 512;
  const bf16* Wb = W + (size_t)n0 * 512;

  const int ibs = wave * 64 + lane;            // per-lane stage index base
#define STAGE(buf, k0)                                                        \
  {                                                                           \
    _Pragma("unroll")                                                         \
    for (int i = 0; i < 4; ++i) {                                             \
      int idx = i * 256 + ibs;                                                \
      gload16(Ab + (size_t)(idx >> 3) * 512 + (k0) + (idx & 7) * 8,           \
              &As[buf][(i * 256 + wave * 64) * 8]);                           \
    }                                                                         \
    _Pragma("unroll")                                                         \
    for (int i = 0; i < 4; ++i) {                                             \
      int idx = i * 256 + ibs;                                                \
      gload16(Wb + (size_t)(idx >> 3) * 512 + (k0) + (idx & 7) * 8,           \
              &Bs[buf][(i * 256 + wave * 64) * 8]);                           \
    }                                                                         \
  }

  STAGE(0, 0);
  __syncthreads();                       // buf0 ready
#pragma unroll
  for (int ks = 0; ks < 8; ++ks) {
    const int cur = ks & 1;
    if (ks < 7) STAGE(cur ^ 1, (ks + 1) * 64);   // in flight during compute
#pragma unroll
    for (int kk = 0; kk < 64; kk += 32) {
      bf16x8 af[4], bf_[4];
#pragma unroll
      for (int mt = 0; mt < 4; ++mt)
        af[mt] = *(const bf16x8*)(&As[cur][(wr * 64 + mt * 16 + frow) * 64 + kk + ksel]);
#pragma unroll
      for (int nt = 0; nt < 4; ++nt)
        bf_[nt] = *(const bf16x8*)(&Bs[cur][(wc * 64 + nt * 16 + frow) * 64 + kk + ksel]);
#pragma unroll
      for (int mt = 0; mt < 4; ++mt)
#pragma unroll
        for (int nt = 0; nt < 4; ++nt)
          acc[mt * 4 + nt] = __builtin_amdgcn_mfma_f32_16x16x32_bf16(
              af[mt], bf_[nt], acc[mt * 4 + nt], 0, 0, 0);
    }
    __syncthreads();                     // drains next-stage DMA + guards reuse
  }
#undef STAGE

  const int rb = (lane >> 4) * 4, cb = lane & 15;
#pragma unroll
  for (int mt = 0; mt < 4; ++mt)
#pragma unroll
    for (int nt = 0; nt < 4; ++nt) {
      f32x4 a = acc[mt * 4 + nt];
#pragma unroll
      for (int r = 0; r < 4; ++r) {
        int row = m0 + wr * 64 + mt * 16 + rb + r;
        int col = n0 + wc * 64 + nt * 16 + cb;
        if (col >= 1552) continue;             // padding cols
        float v = a[r] + bias[col];
        int n = row >> 2, b = row & 3;
        if (col >= 1536) {                     // pb/cb projections, f32
          int j = col - 1536;
          int hh = j & 7;
          outf[(j < 8 ? 0 : 32768) + (b * 8 + hh) * 1024 + n] = v;
        } else {
          int which = col >> 9, hh = (col >> 6) & 7, d = col & 63;
          if (which == 0) v *= 0.125f;         // fold 1/sqrt(HD) into Q
          size_t idx;
          if (which == 2)   // V transposed: [b][h][d][n]
            idx = (((size_t)(64 + b * 8 + hh)) << 16) + (size_t)d * 1024 + n;
          else              // Q,K: [which][b][h][n][d]
            idx = (((size_t)(which * 32 + b * 8 + hh)) << 16) + (size_t)n * 64 + d;
          outb[idx] = __float2bfloat16(v);
        }
      }
    }
}

// ---------------------------------------------------------------------------
// GEMM: C[M,Nout] = A[M,K(kOff..kOff+kLen)] * W^T + bias   (bf16, f32 accum)
// 128 x BN tile, global_load_lds(16B) staging, 4 waves, single-buffered.
// MODE 0: bf16 store. MODE 1: relu+bf16. MODE 4: bf16 split-K partial
// (R13-proven: halves partial traffic, absmax unchanged).
// ---------------------------------------------------------------------------
template<int MODE, int BN>
__global__ __launch_bounds__(256)
void gemm_bt(const bf16* __restrict__ A, const bf16* __restrict__ W,
             const float* __restrict__ bias, bf16* __restrict__ outb,
             float* __restrict__ outf, int M, int Nout, int K, int kLen)
{
  constexpr int NT = BN / 32;
  __shared__ bf16 As[128 * 64];
  __shared__ bf16 Bs[BN * 64];
  const int t = threadIdx.x, lane = t & 63, wave = t >> 6;
  const int m0 = blockIdx.y * 128, n0 = blockIdx.x * BN;
  const int kOff = blockIdx.z * kLen;
  if (MODE == 4) outb += (size_t)blockIdx.z * M * Nout;
  const int wr = wave >> 1, wc = wave & 1;
  const int frow = lane & 15, ksel = (lane >> 4) * 8;
  f32x4 acc[4 * NT] = {};
  const bf16* Ab = A + (size_t)m0 * K;
  const bf16* Wb = W + (size_t)n0 * K;

  for (int k0 = kOff; k0 < kOff + kLen; k0 += 64) {
    __syncthreads();
#pragma unroll
    for (int i = 0; i < 4; ++i) {
      int ib = i * 256 + wave * 64;
      int idx = ib + lane;
      gload16(Ab + (size_t)(idx >> 3) * K + k0 + (idx & 7) * 8, As + ib * 8);
    }
#pragma unroll
    for (int i = 0; i < BN / 32; ++i) {
      int ib = i * 256 + wave * 64;
      int idx = ib + lane;
      gload16(Wb + (size_t)(idx >> 3) * K + k0 + (idx & 7) * 8, Bs + ib * 8);
    }
    __syncthreads();
#pragma unroll
    for (int kk = 0; kk < 64; kk += 32) {
      bf16x8 af[4], bf_[NT];
#pragma unroll
      for (int mt = 0; mt < 4; ++mt)
        af[mt] = *(const bf16x8*)(As + (wr * 64 + mt * 16 + frow) * 64 + kk + ksel);
#pragma unroll
      for (int nt = 0; nt < NT; ++nt)
        bf_[nt] = *(const bf16x8*)(Bs + (wc * (BN / 2) + nt * 16 + frow) * 64 + kk + ksel);
#pragma unroll
      for (int mt = 0; mt < 4; ++mt)
#pragma unroll
        for (int nt = 0; nt < NT; ++nt)
          acc[mt * NT + nt] = __builtin_amdgcn_mfma_f32_16x16x32_bf16(
              af[mt], bf_[nt], acc[mt * NT + nt], 0, 0, 0);
    }
  }
  const int rb = (lane >> 4) * 4, cb = lane & 15;
#pragma unroll
  for (int mt = 0; mt < 4; ++mt)
#pragma unroll
    for (int nt = 0; nt < NT; ++nt) {
      f32x4 a = acc[mt * NT + nt];
#pragma unroll
      for (int r = 0; r < 4; ++r) {
        int row = m0 + wr * 64 + mt * 16 + rb + r;
        int col = n0 + wc * (BN / 2) + nt * 16 + cb;
        if (MODE == 4) {
          outb[(size_t)row * Nout + col] = __float2bfloat16(a[r]);
        } else {
          float v = a[r] + bias[col];
          if (MODE == 1) v = fmaxf(v, 0.f);
          outb[(size_t)row * Nout + col] = __float2bfloat16(v);
        }
      }
    }
}

// ---------------------------------------------------------------------------
// MFMA flash attention, S^T form, UN-split KV (full 1024 keys per block).
// R3/R6-proven body, original grid (x=qchunk, y=h, z=b) — R14's h-innermost
// swap was slightly negative (mask reuse already cache-served; swap
// de-localized K/V panel reads).
// ---------------------------------------------------------------------------
__global__ __launch_bounds__(256, 2)
void attn_mfma(const bf16* __restrict__ qkv, const float* __restrict__ pbw,
               const float* __restrict__ cbw, const uint32_t* __restrict__ mpk,
               bf16* __restrict__ ctxo)
{
  __shared__ bf16 Kt[128 * 64];    // [key][d] swizzled (DMA)
  __shared__ bf16 Vt[64 * 128];    // [d][key] swizzled (DMA)
  __shared__ bf16 Ps[4][16][136];  // per-wave P [q][key], stride 136 -> 2-way
  const int t = threadIdx.x, lane = t & 63, wave = t >> 6;
  const int g = lane >> 4, c = lane & 15;
  const int h = blockIdx.y, b = blockIdx.z;
  const int q0 = blockIdx.x * 64 + wave * 16;
  const size_t bh = (size_t)b * 8 + h;
  const bf16* Qp = qkv + (bh << 16);
  const bf16* Kp = qkv + ((32 + bh) << 16);
  const bf16* Vg = qkv + ((64 + bh) << 16);     // [64 d][1024 n]

  bf16x8 qa0 = *(const bf16x8*)(Qp + (size_t)(q0 + c) * 64 + g * 8);
  bf16x8 qa1 = *(const bf16x8*)(Qp + (size_t)(q0 + c) * 64 + 32 + g * 8);

  const float pbq = pbw[bh * 1024 + q0 + c];
  const float cbq = cbw[bh * 1024 + q0 + c];
  const uint32_t* mrp = mpk + (((size_t)b * 1024 + q0 + c) << 10);

  f32x4 oacc[4] = {{0,0,0,0},{0,0,0,0},{0,0,0,0},{0,0,0,0}};
  float m = -1e30f, l = 0.f;

  for (int kt = 0; kt < 8; ++kt) {
    const int k0 = kt * 128;
    __syncthreads();
#pragma unroll
    for (int i = 0; i < 4; ++i) {    // K DMA: slot (r,p) <- chunk p^(r&7)
      int ib = i * 256 + wave * 64;
      int idx = ib + lane;
      int r = idx >> 3, p = idx & 7;
      gload16(Kp + (size_t)(k0 + r) * 64 + ((p ^ (r & 7)) * 8), Kt + ib * 8);
    }
#pragma unroll
    for (int i = 0; i < 4; ++i) {    // V DMA: slot (d,p) <- chunk p^(d&15)
      int ib = i * 256 + wave * 64;
      int idx = ib + lane;
      int d = idx >> 4, p = idx & 15;
      gload16(Vg + (size_t)d * 1024 + k0 + ((p ^ (d & 15)) * 8), Vt + ib * 8);
    }
    uint4 mu[8];
#pragma unroll
    for (int nt = 0; nt < 8; ++nt)
      mu[nt] = *(const uint4*)(mrp + k0 + nt * 16 + 4 * g);
    __syncthreads();
    f32x4 sacc[8];
#pragma unroll
    for (int nt = 0; nt < 8; ++nt) {
      f32x4 z = {0.f,0.f,0.f,0.f};
      int r = nt * 16 + c;           // r & 7 == c & 7
      bf16x8 k0f = *(const bf16x8*)(Kt + r * 64 + (( g      ^ (c & 7)) * 8));
      bf16x8 k1f = *(const bf16x8*)(Kt + r * 64 + (((4 + g) ^ (c & 7)) * 8));
      z = __builtin_amdgcn_mfma_f32_16x16x32_bf16(k0f, qa0, z, 0, 0, 0);
      z = __builtin_amdgcn_mfma_f32_16x16x32_bf16(k1f, qa1, z, 0, 0, 0);
      sacc[nt] = z;
    }
    float mx = -1e30f;
#pragma unroll
    for (int nt = 0; nt < 8; ++nt) {
      uint32_t uu[4] = {mu[nt].x, mu[nt].y, mu[nt].z, mu[nt].w};
#pragma unroll
      for (int r = 0; r < 4; ++r) {
        float s = sacc[nt][r] + bfhi(uu[r]) * pbq + bflo(uu[r]) * cbq;
        s = (uu[r] == 0xFFFFFFFFu) ? -1e30f : s;
        sacc[nt][r] = s;
        mx = fmaxf(mx, s);
      }
    }
    mx = fmaxf(mx, __shfl_xor(mx, 16));
    mx = fmaxf(mx, __shfl_xor(mx, 32));
    const float newm = fmaxf(m, mx);
    const float al = __expf(m - newm);
    float ps = 0.f;
#pragma unroll
    for (int nt = 0; nt < 8; ++nt) {
      float p0 = (sacc[nt][0] <= -1e29f) ? 0.f : __expf(sacc[nt][0] - newm);
      float p1 = (sacc[nt][1] <= -1e29f) ? 0.f : __expf(sacc[nt][1] - newm);
      float p2 = (sacc[nt][2] <= -1e29f) ? 0.f : __expf(sacc[nt][2] - newm);
      float p3 = (sacc[nt][3] <= -1e29f) ? 0.f : __expf(sacc[nt][3] - newm);
      ps += (p0 + p1) + (p2 + p3);
      uint2 w;
      w.x = (bfbits(p1) << 16) | bfbits(p0);
      w.y = (bfbits(p3) << 16) | bfbits(p2);
      *(uint2*)&Ps[wave][c][nt * 16 + 4 * g] = w;
    }
    ps += __shfl_xor(ps, 16);
    ps += __shfl_xor(ps, 32);
    l = l * al + ps;
    m = newm;
#pragma unroll
    for (int dt = 0; dt < 4; ++dt) {
      oacc[dt][0] *= al; oacc[dt][1] *= al;
      oacc[dt][2] *= al; oacc[dt][3] *= al;
    }
#pragma unroll
    for (int dt = 0; dt < 4; ++dt) {
      int row = dt * 16 + c;         // row & 15 == c
#pragma unroll
      for (int kc = 0; kc < 4; ++kc) {
        bf16x8 vf = *(const bf16x8*)(Vt + row * 128 + (((kc * 4 + g) ^ c) * 8));
        bf16x8 pf = *(const bf16x8*)&Ps[wave][c][kc * 32 + g * 8];
        oacc[dt] = __builtin_amdgcn_mfma_f32_16x16x32_bf16(vf, pf, oacc[dt], 0, 0, 0);
      }
    }
  }
  // normalized direct write: ctx[(q*4 + b)*512 + h*64 + d], bf16
  const int qg = q0 + c;
  const float inv = (l > 0.f) ? 1.f / l : 0.f;
  bf16* out = ctxo + ((size_t)qg * 4 + b) * 512 + h * 64;
#pragma unroll
  for (int dt = 0; dt < 4; ++dt) {
    uint2 w;
    w.x = (bfbits(oacc[dt][1] * inv) << 16) | bfbits(oacc[dt][0] * inv);
    w.y = (bfbits(oacc[dt][3] * inv) << 16) | bfbits(oacc[dt][2] * inv);
    *(uint2*)(out + dt * 16 + 4 * g) = w;
  }
}

// ---------------------------------------------------------------------------
// out = LayerNorm(a + p0 + p1 + bias) * g + be   (row = 512, wave per row)
// TP = partial dtype (bf16 — halves split-K read traffic, R13-proven).
// ---------------------------------------------------------------------------
template<typename TA, typename TP, typename TO>
__global__ __launch_bounds__(256)
void ln_res2(const TA* __restrict__ a, const TP* __restrict__ p0,
             const TP* __restrict__ p1, const float* __restrict__ bias,
             const float* __restrict__ g, const float* __restrict__ be,
             TO* __restrict__ out)
{
  const int wave = threadIdx.x >> 6, lane = threadIdx.x & 63;
  const int m = blockIdx.x * 4 + wave;
  const size_t base = (size_t)m * 512 + lane * 8;
  float va[8], f0[8], f1[8], bb[8];
  load8(a + base, va);
  load8(p0 + base, f0);
  load8(p1 + base, f1);
  load8(bias + lane * 8, bb);
  float v[8], s = 0.f;
#pragma unroll
  for (int j = 0; j < 8; ++j) { v[j] = va[j] + f0[j] + f1[j] + bb[j]; s += v[j]; }
#pragma unroll
  for (int off = 32; off; off >>= 1) s += __shfl_xor(s, off);
  const float mean = s * (1.f / 512.f);
  float q = 0.f;
#pragma unroll
  for (int j = 0; j < 8; ++j) { float d = v[j] - mean; q += d * d; }
#pragma unroll
  for (int off = 32; off; off >>= 1) q += __shfl_xor(q, off);
  const float rs = rsqrtf(q * (1.f / 512.f) + 1e-5f);
  float gv[8], bv[8];
  load8(g + lane * 8, gv);
  load8(be + lane * 8, bv);
#pragma unroll
  for (int j = 0; j < 8; ++j)
    store1(out + base + j, (v[j] - mean) * rs * gv[j] + bv[j]);
}

// ---------------------------------------------------------------------------
extern "C" void kernel_launch(void* const* d_in, const int* in_sizes, int n_in,
                              void* d_out, int out_size, void* d_ws, size_t ws_size,
                              hipStream_t stream)
{
  (void)in_sizes; (void)n_in; (void)out_size; (void)ws_size;
  const float* x    = (const float*)d_in[0];
  const float* pm   = (const float*)d_in[1];
  const int*   hid  = (const int*)d_in[2];
  const int*   padm = (const int*)d_in[3];
  const float* Wp   = (const float*)d_in[4];
  const float* bp   = (const float*)d_in[5];
  const float* Wc   = (const float*)d_in[6];
  const float* bc   = (const float*)d_in[7];
  const float* Wqkv = (const float*)d_in[8];
  const float* bqkv = (const float*)d_in[9];
  const float* Wo   = (const float*)d_in[10];
  const float* bo   = (const float*)d_in[11];
  const float* W1   = (const float*)d_in[12];
  const float* b1   = (const float*)d_in[13];
  const float* W2   = (const float*)d_in[14];
  const float* b2   = (const float*)d_in[15];
  const float* g1   = (const float*)d_in[16];
  const float* be1  = (const float*)d_in[17];
  const float* g2   = (const float*)d_in[18];
  const float* be2  = (const float*)d_in[19];

  // Workspace (lifetimes):
  char* ws = (char*)d_ws;
  bf16*     qkvb  = (bf16*)    (ws);               // 12.58 MB (qkv_gemm -> attn)
  float*    pbo   = (float*)   (ws + 12582912);    // 128 KB
  float*    cbo   = (float*)   (ws + 12713984);    // 128 KB  (= pbo + 32768 el)
  uint32_t* mpk   = (uint32_t*)(ws + 12845056);    // 16.78 MB (prep_mask -> attn)
  bf16*     ctx   = (bf16*)    (ws + 29622272);    // 4.19 MB (attn -> Wo gemm)
  bf16*     partb = (bf16*)    (ws);               // 8.39 MB bf16 split-K partials
  bf16*     ff1   = (bf16*)    (ws + 16777216);    // 16.78 MB (aliases mpk tail + ctx)
  bf16*     y     = (bf16*)    (ws + 33816576);    // 4.19 MB (ln1 -> ln2)
  bf16*     xb    = (bf16*)    (ws + 38010880);    // 4.19 MB
  bf16*     wqkvb = (bf16*)    (ws + 42205184);    // 1.70 MB (1664 x 512 bf16)
  bf16*     wob   = (bf16*)    (ws + 43909120);    // 512 KB
  bf16*     w1b   = (bf16*)    (ws + 44433408);    // 2.10 MB
  bf16*     w2b   = (bf16*)    (ws + 46530560);    // 2.10 MB
  float*    bext  = (float*)   (ws + 48627712);    // 6.5 KB
  bf16*     partb1 = partb + (size_t)4096 * 512;

  prep_mask<<<3077, 256, 0, stream>>>(pm, hid, padm, mpk,
                                      x, Wqkv, Wo, W1, W2, xb, wqkvb, wob, w1b, w2b,
                                      bqkv, bp, bc, Wp, Wc, bext);
  qkv_gemm<<<416, 256, 0, stream>>>(xb, wqkvb, bext, qkvb, pbo);
  attn_mfma<<<dim3(16, 8, 4), 256, 0, stream>>>(qkvb, pbo, cbo, mpk, ctx);
  gemm_bt<4, 64><<<dim3(8, 32, 2), 256, 0, stream>>>(ctx, wob, nullptr, partb, nullptr, 4096, 512, 512, 256);
  ln_res2<float, bf16, bf16><<<1024, 256, 0, stream>>>(x, partb, partb1, bo, g1, be1, y);
  gemm_bt<1, 128><<<dim3(16, 32), 256, 0, stream>>>(y, w1b, b1, ff1, nullptr, 4096, 2048, 512, 512);
  gemm_bt<4, 64><<<dim3(8, 32, 2), 256, 0, stream>>>(ff1, w2b, nullptr, partb, nullptr, 4096, 512, 2048, 1024);
  ln_res2<bf16, bf16, float><<<1024, 256, 0, stream>>>(y, partb, partb1, b2, g2, be2, (float*)d_out);
}